// Round 9
// baseline (2888.421 us; speedup 1.0000x reference)
//
#include <hip/hip_runtime.h>

// GRU LM: L=2, B=64, S=64, E=H=1024, V=32000. All ref math fp32; we use bf16 MFMA.
#define NB_REC 128          // persistent recurrence grid (<= 256 CUs -> co-resident)
#define SBV    131072000    // S*B*V logits element count

typedef __bf16 bf16x8 __attribute__((ext_vector_type(8)));
typedef float  f32x4  __attribute__((ext_vector_type(4)));
typedef unsigned short u16;

__device__ __forceinline__ u16 f2bf(float f) {
  union { float f; unsigned u; } c; c.f = f;
  return (u16)((c.u + 0x7fffu + ((c.u >> 16) & 1u)) >> 16);  // RNE
}
__device__ __forceinline__ float sigm(float x) { return 1.f / (1.f + __expf(-x)); }
__device__ __forceinline__ float tanh_f(float x) { return 2.f / (1.f + __expf(-2.f * x)) - 1.f; }

// ---------------- prep kernels ----------------

__global__ void k_cvtv(const float* __restrict__ src, u16* __restrict__ dst, int n4) {
  const float4* s4 = (const float4*)src;
  ushort4* d4 = (ushort4*)dst;
  for (int i = blockIdx.x * blockDim.x + threadIdx.x; i < n4; i += gridDim.x * blockDim.x) {
    float4 v = s4[i];
    ushort4 o; o.x = f2bf(v.x); o.y = f2bf(v.y); o.z = f2bf(v.z); o.w = f2bf(v.w);
    d4[i] = o;
  }
}

__global__ void k_pack3(const float* __restrict__ sx, const float* __restrict__ sz,
                        const float* __restrict__ sh, int srcOff, u16* __restrict__ dst) {
  int i = blockIdx.x * blockDim.x + threadIdx.x;  // over 3M/4 float4s
  if (i >= 786432) return;
  int g = i >> 18;            // 0..2 gate
  int r4 = i & 262143;        // float4 index within 1M-elem matrix
  const float* s = (g == 0 ? sx : (g == 1 ? sz : sh)) + srcOff;
  float4 v = ((const float4*)s)[r4];
  ushort4 o; o.x = f2bf(v.x); o.y = f2bf(v.y); o.z = f2bf(v.z); o.w = f2bf(v.w);
  ((ushort4*)dst)[i] = o;
}

__global__ void k_embed(const int* __restrict__ idx, const float* __restrict__ emb,
                        u16* __restrict__ xe) {
  int i = blockIdx.x * blockDim.x + threadIdx.x;  // over 4096*256 float4s
  if (i >= 1048576) return;
  int row = i >> 8, k4 = i & 255;
  int e = idx[row];
  float4 v = ((const float4*)emb)[(size_t)e * 256 + k4];
  ushort4 o; o.x = f2bf(v.x); o.y = f2bf(v.y); o.z = f2bf(v.z); o.w = f2bf(v.w);
  ((ushort4*)xe)[i] = o;
}

// ---------------- GEMM: C[M,N] = A[M,K] @ B[N,K]^T (+bias), bf16 in / fp32 out ----------------
template<bool BIAS>
__global__ __launch_bounds__(256) void gemm_bt(const u16* __restrict__ A, const u16* __restrict__ Bm,
                                               float* __restrict__ C, const float* __restrict__ bias,
                                               int M, int N, int K, int mtiles) {
  __shared__ u16 As[128 * 32];
  __shared__ u16 Bs[128 * 32];
  const int tid = threadIdx.x;
  const int bm = blockIdx.x % mtiles, bn = blockIdx.x / mtiles;
  const int m0 = bm * 128, n0 = bn * 128;
  const int lane = tid & 63, w = tid >> 6, wm = w & 1, wn = w >> 1;
  const int la = lane & 15, lk = lane >> 4;
  const int srow = tid >> 2, sk = (tid & 3) * 8;
  f32x4 acc[4][4] = {};
  for (int kt = 0; kt < K; kt += 32) {
    const u16* srcA0 = A + (size_t)(m0 + srow) * K + kt + sk;
    const u16* srcA1 = A + (size_t)(m0 + srow + 64) * K + kt + sk;
    const u16* srcB0 = Bm + (size_t)(n0 + srow) * K + kt + sk;
    const u16* srcB1 = Bm + (size_t)(n0 + srow + 64) * K + kt + sk;
    __builtin_amdgcn_global_load_lds((const __attribute__((address_space(1))) void*)srcA0,
        (__attribute__((address_space(3))) void*)((char*)As + tid * 16), 16, 0, 0);
    __builtin_amdgcn_global_load_lds((const __attribute__((address_space(1))) void*)srcA1,
        (__attribute__((address_space(3))) void*)((char*)As + 4096 + tid * 16), 16, 0, 0);
    __builtin_amdgcn_global_load_lds((const __attribute__((address_space(1))) void*)srcB0,
        (__attribute__((address_space(3))) void*)((char*)Bs + tid * 16), 16, 0, 0);
    __builtin_amdgcn_global_load_lds((const __attribute__((address_space(1))) void*)srcB1,
        (__attribute__((address_space(3))) void*)((char*)Bs + 4096 + tid * 16), 16, 0, 0);
    __syncthreads();
    bf16x8 av[4], bv[4];
    #pragma unroll
    for (int m = 0; m < 4; ++m)
      av[m] = *(const bf16x8*)(As + (wm * 64 + m * 16 + la) * 32 + lk * 8);
    #pragma unroll
    for (int n = 0; n < 4; ++n)
      bv[n] = *(const bf16x8*)(Bs + (wn * 64 + n * 16 + la) * 32 + lk * 8);
    #pragma unroll
    for (int m = 0; m < 4; ++m)
      #pragma unroll
      for (int n = 0; n < 4; ++n)
        acc[m][n] = __builtin_amdgcn_mfma_f32_16x16x32_bf16(av[m], bv[n], acc[m][n], 0, 0, 0);
    __syncthreads();
  }
  #pragma unroll
  for (int n = 0; n < 4; ++n) {
    const int gc = n0 + wn * 64 + n * 16 + la;
    const float bb = BIAS ? bias[gc] : 0.f;
    #pragma unroll
    for (int m = 0; m < 4; ++m) {
      const int gr0 = m0 + wm * 64 + m * 16 + lk * 4;
      #pragma unroll
      for (int r = 0; r < 4; ++r)
        C[(size_t)(gr0 + r) * N + gc] = acc[m][n][r] + bb;
    }
  }
}

// ---------------- persistent recurrence (weight-stationary) ----------------
// 128 blocks: bid<64 -> layer 0, bid>=64 -> layer 1; each owns cols [jb*16, +16).
// U-gate weight slice (3 x 16 rows x 1024 k = 96KB) lives in LDS for the whole
// kernel -> ZERO per-iteration weight HBM traffic (r6's 483MB pathology).
// L1's W slice (96KB/block) streams via plain loads -> L2-resident.
// Activations: written sc1 (write-through to LLC), read with PLAIN cached loads.
// Correct because every cross-block address is write-once-per-launch and read
// only after its flag; one agent-acquire fence at kernel ENTRY drops stale lines
// from previous graph replays (per-phase fences were the r1 637MB pathology).
// Polling: WAVE 0 ONLY (waves 1-3 park at __syncthreads) -> 4x less LLC poll
// traffic; hang guard ~25ms/wait so bugs fail validation fast, never wedge.

__device__ __forceinline__ void waitg64(const unsigned* f, unsigned tgt, int tid) {
  if (tgt && tid < 64) {
    unsigned g = 0;
    while (true) {
      bool ok = true;
      if (tid < 16) {
        uint4 v; const uint4* p = (const uint4*)f + tid;
        asm volatile("global_load_dwordx4 %0, %1, off sc1\ns_waitcnt vmcnt(0)"
                     : "=v"(v) : "v"(p) : "memory");
        ok = v.x >= tgt && v.y >= tgt && v.z >= tgt && v.w >= tgt;
      }
      if (__all(ok)) break;
      __builtin_amdgcn_s_sleep(1);
      if (++g > 1000000u) break;  // hang guard (~25ms)
    }
  }
  __syncthreads();
}

__device__ __forceinline__ void waitg2x(const unsigned* f0, unsigned t0,
                                        const unsigned* f1, unsigned t1, int tid) {
  if (tid < 64) {
    unsigned g = 0;
    while (true) {
      bool ok = true;
      if (tid < 32) {
        const unsigned* f = (tid < 16) ? f0 : f1;
        unsigned tgt = (tid < 16) ? t0 : t1;
        if (tgt) {
          uint4 v; const uint4* p = (const uint4*)f + (tid & 15);
          asm volatile("global_load_dwordx4 %0, %1, off sc1\ns_waitcnt vmcnt(0)"
                       : "=v"(v) : "v"(p) : "memory");
          ok = v.x >= tgt && v.y >= tgt && v.z >= tgt && v.w >= tgt;
        }
      }
      if (__all(ok)) break;
      __builtin_amdgcn_s_sleep(1);
      if (++g > 1000000u) break;
    }
  }
  __syncthreads();
}

__device__ __forceinline__ void arrive(unsigned* myFlag, unsigned val, int tid) {
  asm volatile("s_waitcnt vmcnt(0)" ::: "memory");   // per-wave: my sc1 stores at LLC
  __syncthreads();                                    // all waves drained
  if (tid == 0)
    asm volatile("global_store_dword %0, %1, off sc1" :: "v"(myFlag), "v"(val) : "memory");
}

__global__ __launch_bounds__(256) void k_recur(
    const u16* __restrict__ hinitb,    // [2][64][1024] bf16 of initial hidden
    const float* __restrict__ hidden,  // [2][64][1024] fp32
    const float* __restrict__ X0,      // [64][64][3072] layer-0 x-projections
    const u16* __restrict__ Ucat0, const u16* __restrict__ Ucat1,  // [3072][1024] {Ur|Uz|Uh}
    const u16* __restrict__ Wcat1,                                  // [3072][1024] {Wx|Wz|Wh} layer1
    const float* __restrict__ br, const float* __restrict__ bz, const float* __restrict__ bh,
    u16* __restrict__ H0seq, u16* __restrict__ H1seq,  // [64][64][1024] bf16 hidden per step
    u16* __restrict__ RH0, u16* __restrict__ RH1,      // [64][64][1024] bf16 r*h per step
    float* __restrict__ houtf,                          // d_out + SBV : [2][64][1024]
    unsigned* flags) {
  extern __shared__ char sW[];        // 96KB: 3 gates x [16 rows][1024 k], XOR-swizzled
  const int tid = threadIdx.x, bid = blockIdx.x;
  const int layer = bid >> 6, jb = bid & 63, j0 = jb * 16;
  const int lane = tid & 63, w = tid >> 6;
  const int la = lane & 15, lk = lane >> 4;
  const int jl = j0 + la;             // this lane's output col (C/D: col = lane&15)
  const int row0 = w * 16;            // wave's 16 batch rows
  const u16* Ucat = layer ? Ucat1 : Ucat0;
  u16* Hseq = layer ? H1seq : H0seq;
  u16* RHl = layer ? RH1 : RH0;
  const u16* hinit = hinitb + layer * 65536;
  unsigned* fSelf = flags + layer * 64;
  const unsigned* fL0 = flags;
  unsigned* myFlag = fSelf + jb;

  // drop stale L1/L2 lines from previous graph replay (ONCE per launch)
  __builtin_amdgcn_fence(__ATOMIC_ACQUIRE, "agent");

  // ---- stage U weight slice into LDS (once): 6144 16B-chunks / 256 thr = 24 each ----
  const int xorv = (la & 7) << 4;
  for (int i = 0; i < 24; ++i) {
    int c = i * 256 + tid;                       // 0..6143
    int g = c >> 11, rem = c & 2047;             // 2048 chunks per gate
    int urow = rem >> 7, kc = rem & 127;
    uint4 v = *(const uint4*)(Ucat + ((size_t)((g << 10) + j0 + urow)) * 1024 + kc * 8);
    *(uint4*)(sW + (g << 15) + urow * 2048 + ((kc * 16) ^ ((urow & 7) << 4))) = v;
  }
  __syncthreads();
  const char* sWla = sW + la * 2048;             // per-lane weight row base

  float h_reg[4], z_reg[4];
  #pragma unroll
  for (int r = 0; r < 4; ++r)
    h_reg[r] = hidden[layer * 65536 + (row0 + lk * 4 + r) * 1024 + jl];
  const float bR = br[layer * 1024 + jl], bZ = bz[layer * 1024 + jl], bH = bh[layer * 1024 + jl];

  // L1 W-stream row bases (B-operand: row = col j0+la), plain loads -> L2-resident slice
  const u16* WrR = Wcat1 + (size_t)(j0 + la) * 1024 + lk * 8;
  const u16* WrZ = WrR + (size_t)1024 * 1024;
  const u16* WrH = WrR + (size_t)2048 * 1024;

  for (int t = 0; t < 64; ++t) {
    // ================= phase A: r,z gates =================
    if (layer == 0) waitg64(fSelf, 2 * t, tid);
    else            waitg2x(fSelf, 2 * t, fL0, 2 * t + 2, tid);
    const u16* hsrc = (t == 0) ? hinit : (Hseq + (size_t)(t - 1) * 65536);
    const u16* ap = hsrc + (size_t)(row0 + la) * 1024 + lk * 8;
    f32x4 accR = {0.f, 0.f, 0.f, 0.f}, accZ = {0.f, 0.f, 0.f, 0.f};
    if (layer == 0) {
      #pragma unroll 8
      for (int ks = 0; ks < 32; ++ks) {
        const int kx = (ks * 64 + lk * 16) ^ xorv;
        bf16x8 a = *(const bf16x8*)(ap + ks * 32);
        accR = __builtin_amdgcn_mfma_f32_16x16x32_bf16(a, *(const bf16x8*)(sWla + kx), accR, 0, 0, 0);
        accZ = __builtin_amdgcn_mfma_f32_16x16x32_bf16(a, *(const bf16x8*)(sWla + 32768 + kx), accZ, 0, 0, 0);
      }
    } else {
      const u16* xp = H0seq + (size_t)t * 65536 + (size_t)(row0 + la) * 1024 + lk * 8;
      #pragma unroll 4
      for (int ks = 0; ks < 32; ++ks) {
        const int kx = (ks * 64 + lk * 16) ^ xorv;
        bf16x8 a = *(const bf16x8*)(ap + ks * 32);
        bf16x8 x = *(const bf16x8*)(xp + ks * 32);
        accR = __builtin_amdgcn_mfma_f32_16x16x32_bf16(a, *(const bf16x8*)(sWla + kx), accR, 0, 0, 0);
        accZ = __builtin_amdgcn_mfma_f32_16x16x32_bf16(a, *(const bf16x8*)(sWla + 32768 + kx), accZ, 0, 0, 0);
        accR = __builtin_amdgcn_mfma_f32_16x16x32_bf16(x, *(const bf16x8*)(WrR + ks * 32), accR, 0, 0, 0);
        accZ = __builtin_amdgcn_mfma_f32_16x16x32_bf16(x, *(const bf16x8*)(WrZ + ks * 32), accZ, 0, 0, 0);
      }
    }
    #pragma unroll
    for (int r = 0; r < 4; ++r) {
      const int row = row0 + lk * 4 + r;  // C/D: row = (lane>>4)*4 + reg
      float pr = accR[r] + bR, pz = accZ[r] + bZ;
      if (layer == 0) {
        const float* xf = X0 + (size_t)(t * 64 + row) * 3072 + jl;
        pr += xf[0]; pz += xf[1024];
      }
      float rv = sigm(pr);
      z_reg[r] = sigm(pz);
      unsigned v = f2bf(rv * h_reg[r]);
      u16* p = RHl + (size_t)(t * 64 + row) * 1024 + jl;
      asm volatile("global_store_short %0, %1, off sc1" :: "v"(p), "v"(v));
    }
    arrive(myFlag, 2 * t + 1, tid);
    // ================= phase B: candidate + state update =================
    waitg64(fSelf, 2 * t + 1, tid);
    const u16* rp = RHl + (size_t)t * 65536 + (size_t)(row0 + la) * 1024 + lk * 8;
    f32x4 accH = {0.f, 0.f, 0.f, 0.f};
    if (layer == 0) {
      #pragma unroll 8
      for (int ks = 0; ks < 32; ++ks) {
        const int kx = (ks * 64 + lk * 16) ^ xorv;
        bf16x8 a = *(const bf16x8*)(rp + ks * 32);
        accH = __builtin_amdgcn_mfma_f32_16x16x32_bf16(a, *(const bf16x8*)(sWla + 65536 + kx), accH, 0, 0, 0);
      }
    } else {
      const u16* xp = H0seq + (size_t)t * 65536 + (size_t)(row0 + la) * 1024 + lk * 8;
      #pragma unroll 8
      for (int ks = 0; ks < 32; ++ks) {
        const int kx = (ks * 64 + lk * 16) ^ xorv;
        bf16x8 a = *(const bf16x8*)(rp + ks * 32);
        bf16x8 x = *(const bf16x8*)(xp + ks * 32);
        accH = __builtin_amdgcn_mfma_f32_16x16x32_bf16(a, *(const bf16x8*)(sWla + 65536 + kx), accH, 0, 0, 0);
        accH = __builtin_amdgcn_mfma_f32_16x16x32_bf16(x, *(const bf16x8*)(WrH + ks * 32), accH, 0, 0, 0);
      }
    }
    #pragma unroll
    for (int r = 0; r < 4; ++r) {
      const int row = row0 + lk * 4 + r;
      float pre = accH[r] + bH;
      if (layer == 0) pre += X0[(size_t)(t * 64 + row) * 3072 + 2048 + jl];
      float hc = tanh_f(pre);
      float hn = h_reg[r] + z_reg[r] * (hc - h_reg[r]);  // (1-z)h + z*hcand
      h_reg[r] = hn;
      unsigned v = f2bf(hn);
      u16* p = Hseq + (size_t)(t * 64 + row) * 1024 + jl;
      asm volatile("global_store_short %0, %1, off sc1" :: "v"(p), "v"(v));
      if (t == 63) houtf[layer * 65536 + row * 1024 + jl] = hn;
    }
    arrive(myFlag, 2 * t + 2, tid);
  }
}

// ---------------- host launch ----------------
extern "C" void kernel_launch(void* const* d_in, const int* in_sizes, int n_in,
                              void* d_out, int out_size, void* d_ws, size_t ws_size,
                              hipStream_t stream) {
  const int* inputs = (const int*)d_in[0];
  const float* hidden = (const float*)d_in[1];
  const float* emb = (const float*)d_in[2];
  const float* Wx = (const float*)d_in[3];
  const float* Ur = (const float*)d_in[4];
  const float* br = (const float*)d_in[5];
  const float* Wz = (const float*)d_in[6];
  const float* Uz = (const float*)d_in[7];
  const float* bz = (const float*)d_in[8];
  const float* Wh = (const float*)d_in[9];
  const float* Uh = (const float*)d_in[10];
  const float* bh = (const float*)d_in[11];
  const float* decW = (const float*)d_in[12];
  const float* decb = (const float*)d_in[13];
  float* out = (float*)d_out;

  char* ws = (char*)d_ws;
  size_t off = 0;
  auto alloc = [&](size_t bytes) { char* p = ws + off; off += (bytes + 255) & ~(size_t)255; return p; };
  unsigned* flags = (unsigned*)alloc(4096);   // [0..63]=L0, [64..127]=L1
  u16* hinitb = (u16*)alloc((size_t)2 * 64 * 1024 * 2);
  u16* xe     = (u16*)alloc((size_t)4096 * 1024 * 2);
  u16* Wcat0b = (u16*)alloc((size_t)3072 * 1024 * 2);
  u16* Wcat1b = (u16*)alloc((size_t)3072 * 1024 * 2);
  u16* Ucat0b = (u16*)alloc((size_t)3072 * 1024 * 2);
  u16* Ucat1b = (u16*)alloc((size_t)3072 * 1024 * 2);
  u16* decWb  = (u16*)alloc((size_t)32000 * 1024 * 2);
  float* X0   = (float*)alloc((size_t)4096 * 3072 * 4);
  u16* H0seq  = (u16*)alloc((size_t)4096 * 1024 * 2);
  u16* H1seq  = (u16*)alloc((size_t)4096 * 1024 * 2);
  u16* RH0    = (u16*)alloc((size_t)4096 * 1024 * 2);
  u16* RH1    = (u16*)alloc((size_t)4096 * 1024 * 2);

  hipMemsetAsync(flags, 0, 4096, stream);
  k_cvtv<<<128, 256, 0, stream>>>(hidden, hinitb, 32768);
  k_pack3<<<3072, 256, 0, stream>>>(Wx, Wz, Wh, 0, Wcat0b);
  k_pack3<<<3072, 256, 0, stream>>>(Wx, Wz, Wh, 1048576, Wcat1b);
  k_pack3<<<3072, 256, 0, stream>>>(Ur, Uz, Uh, 0, Ucat0b);
  k_pack3<<<3072, 256, 0, stream>>>(Ur, Uz, Uh, 1048576, Ucat1b);
  k_embed<<<4096, 256, 0, stream>>>(inputs, emb, xe);
  k_cvtv<<<4096, 256, 0, stream>>>(decW, decWb, 8192000);

  // layer-0 x-projections for all timesteps: [4096,1024] @ [3072,1024]^T
  gemm_bt<false><<<768, 256, 0, stream>>>(xe, Wcat0b, X0, nullptr, 4096, 3072, 1024, 32);

  // weight-stationary pipelined 2-layer recurrence (96KB dynamic LDS per block)
  (void)hipFuncSetAttribute(reinterpret_cast<const void*>(&k_recur),
                            hipFuncAttributeMaxDynamicSharedMemorySize, 98304);
  k_recur<<<NB_REC, 256, 98304, stream>>>(hinitb, hidden, X0, Ucat0b, Ucat1b, Wcat1b,
                                          br, bz, bh, H0seq, H1seq, RH0, RH1,
                                          out + (size_t)SBV, flags);

  // decoder: logits[4096,32000] = H1seq @ decW^T + bias
  gemm_bt<true><<<8000, 256, 0, stream>>>(H1seq, decWb, out, decb, 4096, 32000, 1024, 32);
}

// Round 10
// 2479.698 us; speedup vs baseline: 1.1648x; 1.1648x over previous
//
#include <hip/hip_runtime.h>

// GRU LM: L=2, B=64, S=64, E=H=1024, V=32000. All ref math fp32; we use bf16 MFMA.
#define SBV 131072000    // S*B*V logits element count

typedef __bf16 bf16x8 __attribute__((ext_vector_type(8)));
typedef float  f32x4  __attribute__((ext_vector_type(4)));
typedef unsigned short u16;

__device__ __forceinline__ u16 f2bf(float f) {
  union { float f; unsigned u; } c; c.f = f;
  return (u16)((c.u + 0x7fffu + ((c.u >> 16) & 1u)) >> 16);  // RNE
}
__device__ __forceinline__ float sigm(float x) { return 1.f / (1.f + __expf(-x)); }
__device__ __forceinline__ float tanh_f(float x) { return 2.f / (1.f + __expf(-2.f * x)) - 1.f; }

// ---------------- prep kernels ----------------

__global__ void k_cvtv(const float* __restrict__ src, u16* __restrict__ dst, int n4) {
  const float4* s4 = (const float4*)src;
  ushort4* d4 = (ushort4*)dst;
  for (int i = blockIdx.x * blockDim.x + threadIdx.x; i < n4; i += gridDim.x * blockDim.x) {
    float4 v = s4[i];
    ushort4 o; o.x = f2bf(v.x); o.y = f2bf(v.y); o.z = f2bf(v.z); o.w = f2bf(v.w);
    d4[i] = o;
  }
}

__global__ void k_pack3(const float* __restrict__ sx, const float* __restrict__ sz,
                        const float* __restrict__ sh, int srcOff, u16* __restrict__ dst) {
  int i = blockIdx.x * blockDim.x + threadIdx.x;  // over 3M/4 float4s
  if (i >= 786432) return;
  int g = i >> 18;            // 0..2 gate
  int r4 = i & 262143;        // float4 index within 1M-elem matrix
  const float* s = (g == 0 ? sx : (g == 1 ? sz : sh)) + srcOff;
  float4 v = ((const float4*)s)[r4];
  ushort4 o; o.x = f2bf(v.x); o.y = f2bf(v.y); o.z = f2bf(v.z); o.w = f2bf(v.w);
  ((ushort4*)dst)[i] = o;
}

__global__ void k_embed(const int* __restrict__ idx, const float* __restrict__ emb,
                        u16* __restrict__ xe) {
  int i = blockIdx.x * blockDim.x + threadIdx.x;  // over 4096*256 float4s
  if (i >= 1048576) return;
  int row = i >> 8, k4 = i & 255;
  int e = idx[row];
  float4 v = ((const float4*)emb)[(size_t)e * 256 + k4];
  ushort4 o; o.x = f2bf(v.x); o.y = f2bf(v.y); o.z = f2bf(v.z); o.w = f2bf(v.w);
  ((ushort4*)xe)[i] = o;
}

// ---------------- GEMM: C[M,N] = A[M,K] @ B[N,K]^T, bf16 in / fp32 out (X0 only) ----------------
__global__ __launch_bounds__(256) void gemm_bt(const u16* __restrict__ A, const u16* __restrict__ Bm,
                                               float* __restrict__ C, int M, int N, int K, int mtiles) {
  __shared__ u16 As[128 * 32];
  __shared__ u16 Bs[128 * 32];
  const int tid = threadIdx.x;
  const int bm = blockIdx.x % mtiles, bn = blockIdx.x / mtiles;
  const int m0 = bm * 128, n0 = bn * 128;
  const int lane = tid & 63, w = tid >> 6, wm = w & 1, wn = w >> 1;
  const int la = lane & 15, lk = lane >> 4;
  const int srow = tid >> 2, sk = (tid & 3) * 8;
  f32x4 acc[4][4] = {};
  for (int kt = 0; kt < K; kt += 32) {
    const u16* srcA0 = A + (size_t)(m0 + srow) * K + kt + sk;
    const u16* srcA1 = A + (size_t)(m0 + srow + 64) * K + kt + sk;
    const u16* srcB0 = Bm + (size_t)(n0 + srow) * K + kt + sk;
    const u16* srcB1 = Bm + (size_t)(n0 + srow + 64) * K + kt + sk;
    __builtin_amdgcn_global_load_lds((const __attribute__((address_space(1))) void*)srcA0,
        (__attribute__((address_space(3))) void*)((char*)As + tid * 16), 16, 0, 0);
    __builtin_amdgcn_global_load_lds((const __attribute__((address_space(1))) void*)srcA1,
        (__attribute__((address_space(3))) void*)((char*)As + 4096 + tid * 16), 16, 0, 0);
    __builtin_amdgcn_global_load_lds((const __attribute__((address_space(1))) void*)srcB0,
        (__attribute__((address_space(3))) void*)((char*)Bs + tid * 16), 16, 0, 0);
    __builtin_amdgcn_global_load_lds((const __attribute__((address_space(1))) void*)srcB1,
        (__attribute__((address_space(3))) void*)((char*)Bs + 4096 + tid * 16), 16, 0, 0);
    __syncthreads();
    bf16x8 av[4], bv[4];
    #pragma unroll
    for (int m = 0; m < 4; ++m)
      av[m] = *(const bf16x8*)(As + (wm * 64 + m * 16 + la) * 32 + lk * 8);
    #pragma unroll
    for (int n = 0; n < 4; ++n)
      bv[n] = *(const bf16x8*)(Bs + (wn * 64 + n * 16 + la) * 32 + lk * 8);
    #pragma unroll
    for (int m = 0; m < 4; ++m)
      #pragma unroll
      for (int n = 0; n < 4; ++n)
        acc[m][n] = __builtin_amdgcn_mfma_f32_16x16x32_bf16(av[m], bv[n], acc[m][n], 0, 0, 0);
    __syncthreads();
  }
  #pragma unroll
  for (int n = 0; n < 4; ++n) {
    const int gc = n0 + wn * 64 + n * 16 + la;
    #pragma unroll
    for (int m = 0; m < 4; ++m) {
      const int gr0 = m0 + wm * 64 + m * 16 + lk * 4;
      #pragma unroll
      for (int r = 0; r < 4; ++r)
        C[(size_t)(gr0 + r) * N + gc] = acc[m][n][r];
    }
  }
}

// ---------------- fused persistent kernel: recurrence + flag-chasing decoder ----------------
// Blocks 0..127: weight-stationary GRU recurrence (r9 design, validated).
// Blocks 128..252: decoder workers; block d owns logits cols [d*256,+256), waits for
// L1 flags >= 2t+2 then computes logits[t] rows from H1seq[t]. Decoder work (~4us/t)
// hides entirely under the recurrence's ~36us/t latency-bound phases.
// Coherence: sc1 write-through stores + sc1 flag polls; plain cached reads of
// write-once data strictly after flag; ONE agent-acquire fence at kernel entry.

__device__ __forceinline__ void waitg64(const unsigned* f, unsigned tgt, int tid) {
  if (tgt && tid < 64) {
    unsigned g = 0;
    while (true) {
      bool ok = true;
      if (tid < 16) {
        uint4 v; const uint4* p = (const uint4*)f + tid;
        asm volatile("global_load_dwordx4 %0, %1, off sc1\ns_waitcnt vmcnt(0)"
                     : "=v"(v) : "v"(p) : "memory");
        ok = v.x >= tgt && v.y >= tgt && v.z >= tgt && v.w >= tgt;
      }
      if (__all(ok)) break;
      __builtin_amdgcn_s_sleep(1);
      if (++g > 1000000u) break;  // hang guard (~25ms)
    }
  }
  __syncthreads();
}

__device__ __forceinline__ void waitg2x(const unsigned* f0, unsigned t0,
                                        const unsigned* f1, unsigned t1, int tid) {
  if (tid < 64) {
    unsigned g = 0;
    while (true) {
      bool ok = true;
      if (tid < 32) {
        const unsigned* f = (tid < 16) ? f0 : f1;
        unsigned tgt = (tid < 16) ? t0 : t1;
        if (tgt) {
          uint4 v; const uint4* p = (const uint4*)f + (tid & 15);
          asm volatile("global_load_dwordx4 %0, %1, off sc1\ns_waitcnt vmcnt(0)"
                       : "=v"(v) : "v"(p) : "memory");
          ok = v.x >= tgt && v.y >= tgt && v.z >= tgt && v.w >= tgt;
        }
      }
      if (__all(ok)) break;
      __builtin_amdgcn_s_sleep(1);
      if (++g > 1000000u) break;
    }
  }
  __syncthreads();
}

__device__ __forceinline__ void arrive(unsigned* myFlag, unsigned val, int tid) {
  asm volatile("s_waitcnt vmcnt(0)" ::: "memory");   // per-wave: my sc1 stores at LLC
  __syncthreads();                                    // all waves drained
  if (tid == 0)
    asm volatile("global_store_dword %0, %1, off sc1" :: "v"(myFlag), "v"(val) : "memory");
}

__global__ __launch_bounds__(256) void k_fused(
    const u16* __restrict__ hinitb,    // [2][64][1024] bf16 of initial hidden
    const float* __restrict__ hidden,  // [2][64][1024] fp32
    const float* __restrict__ X0,      // [64][64][3072] layer-0 x-projections
    const u16* __restrict__ Ucat0, const u16* __restrict__ Ucat1,  // [3072][1024] {Ur|Uz|Uh}
    const u16* __restrict__ Wcat1,                                  // [3072][1024] {Wx|Wz|Wh} layer1
    const float* __restrict__ br, const float* __restrict__ bz, const float* __restrict__ bh,
    u16* __restrict__ H0seq, u16* __restrict__ H1seq,  // [64][64][1024] bf16 hidden per step
    u16* __restrict__ RH0, u16* __restrict__ RH1,      // [64][64][1024] bf16 r*h per step
    const u16* __restrict__ decWb,     // [32000][1024] bf16 decoder weights
    const float* __restrict__ decb,    // [32000]
    float* __restrict__ out,           // logits [64*64][32000]; hfinal at out+SBV
    unsigned* flags) {
  extern __shared__ char sW[];        // 96KB (recurrence blocks): 3 x [16][1024] swizzled
  const int tid = threadIdx.x, bid = blockIdx.x;
  const int lane = tid & 63, w = tid >> 6;
  const int la = lane & 15, lk = lane >> 4;

  // drop stale L1/L2 lines from previous graph replay (ONCE per launch, all blocks)
  __builtin_amdgcn_fence(__ATOMIC_ACQUIRE, "agent");

  if (bid >= 128) {
    // ================= decoder worker =================
    const int d = bid - 128;          // 0..124
    const int c0 = d * 256 + w * 64;  // wave's 64-col strip
    float bb[4];
    #pragma unroll
    for (int nf = 0; nf < 4; ++nf) bb[nf] = decb[c0 + nf * 16 + la];
    const u16* Bp[4];
    #pragma unroll
    for (int nf = 0; nf < 4; ++nf)
      Bp[nf] = decWb + (size_t)(c0 + nf * 16 + la) * 1024 + lk * 8;
    for (int t = 0; t < 64; ++t) {
      waitg64(flags + 64, 2 * t + 2, tid);     // H1seq[t] complete
      const u16* Ab = H1seq + (size_t)t * 65536;
      const u16* Ap[4];
      #pragma unroll
      for (int mf = 0; mf < 4; ++mf) Ap[mf] = Ab + (mf * 16 + la) * 1024 + lk * 8;
      f32x4 acc[4][4] = {};
      #pragma unroll 4
      for (int ks = 0; ks < 32; ++ks) {
        bf16x8 av[4], bv[4];
        #pragma unroll
        for (int mf = 0; mf < 4; ++mf) av[mf] = *(const bf16x8*)(Ap[mf] + ks * 32);
        #pragma unroll
        for (int nf = 0; nf < 4; ++nf) bv[nf] = *(const bf16x8*)(Bp[nf] + ks * 32);
        #pragma unroll
        for (int mf = 0; mf < 4; ++mf)
          #pragma unroll
          for (int nf = 0; nf < 4; ++nf)
            acc[mf][nf] = __builtin_amdgcn_mfma_f32_16x16x32_bf16(av[mf], bv[nf], acc[mf][nf], 0, 0, 0);
      }
      #pragma unroll
      for (int mf = 0; mf < 4; ++mf)
        #pragma unroll
        for (int nf = 0; nf < 4; ++nf) {
          const size_t rb = (size_t)(t * 64 + mf * 16 + lk * 4) * 32000 + c0 + nf * 16 + la;
          #pragma unroll
          for (int r = 0; r < 4; ++r)
            out[rb + (size_t)r * 32000] = acc[mf][nf][r] + bb[nf];
        }
    }
    return;
  }

  // ================= recurrence block =================
  const int layer = bid >> 6, jb = bid & 63, j0 = jb * 16;
  const int jl = j0 + la;             // this lane's output col (C/D: col = lane&15)
  const int row0 = w * 16;            // wave's 16 batch rows
  const u16* Ucat = layer ? Ucat1 : Ucat0;
  u16* Hseq = layer ? H1seq : H0seq;
  u16* RHl = layer ? RH1 : RH0;
  const u16* hinit = hinitb + layer * 65536;
  unsigned* fSelf = flags + layer * 64;
  const unsigned* fL0 = flags;
  unsigned* myFlag = fSelf + jb;
  float* houtf = out + (size_t)SBV;

  // ---- stage U weight slice into LDS (once): 6144 16B-chunks / 256 thr = 24 each ----
  const int xorv = (la & 7) << 4;
  for (int i = 0; i < 24; ++i) {
    int c = i * 256 + tid;                       // 0..6143
    int g = c >> 11, rem = c & 2047;             // 2048 chunks per gate
    int urow = rem >> 7, kc = rem & 127;
    uint4 v = *(const uint4*)(Ucat + ((size_t)((g << 10) + j0 + urow)) * 1024 + kc * 8);
    *(uint4*)(sW + (g << 15) + urow * 2048 + ((kc * 16) ^ ((urow & 7) << 4))) = v;
  }
  __syncthreads();
  const char* sWla = sW + la * 2048;             // per-lane weight row base

  float h_reg[4], z_reg[4];
  #pragma unroll
  for (int r = 0; r < 4; ++r)
    h_reg[r] = hidden[layer * 65536 + (row0 + lk * 4 + r) * 1024 + jl];
  const float bR = br[layer * 1024 + jl], bZ = bz[layer * 1024 + jl], bH = bh[layer * 1024 + jl];

  // L1 W-stream row bases (B-operand: row = col j0+la), plain loads -> L2-resident slice
  const u16* WrR = Wcat1 + (size_t)(j0 + la) * 1024 + lk * 8;
  const u16* WrZ = WrR + (size_t)1024 * 1024;
  const u16* WrH = WrR + (size_t)2048 * 1024;

  for (int t = 0; t < 64; ++t) {
    // ================= phase A: r,z gates =================
    if (layer == 0) waitg64(fSelf, 2 * t, tid);
    else            waitg2x(fSelf, 2 * t, fL0, 2 * t + 2, tid);
    const u16* hsrc = (t == 0) ? hinit : (Hseq + (size_t)(t - 1) * 65536);
    const u16* ap = hsrc + (size_t)(row0 + la) * 1024 + lk * 8;
    f32x4 accR = {0.f, 0.f, 0.f, 0.f}, accZ = {0.f, 0.f, 0.f, 0.f};
    if (layer == 0) {
      #pragma unroll 16
      for (int ks = 0; ks < 32; ++ks) {
        const int kx = (ks * 64 + lk * 16) ^ xorv;
        bf16x8 a = *(const bf16x8*)(ap + ks * 32);
        accR = __builtin_amdgcn_mfma_f32_16x16x32_bf16(a, *(const bf16x8*)(sWla + kx), accR, 0, 0, 0);
        accZ = __builtin_amdgcn_mfma_f32_16x16x32_bf16(a, *(const bf16x8*)(sWla + 32768 + kx), accZ, 0, 0, 0);
      }
    } else {
      const u16* xp = H0seq + (size_t)t * 65536 + (size_t)(row0 + la) * 1024 + lk * 8;
      #pragma unroll 8
      for (int ks = 0; ks < 32; ++ks) {
        const int kx = (ks * 64 + lk * 16) ^ xorv;
        bf16x8 a = *(const bf16x8*)(ap + ks * 32);
        bf16x8 x = *(const bf16x8*)(xp + ks * 32);
        accR = __builtin_amdgcn_mfma_f32_16x16x32_bf16(a, *(const bf16x8*)(sWla + kx), accR, 0, 0, 0);
        accZ = __builtin_amdgcn_mfma_f32_16x16x32_bf16(a, *(const bf16x8*)(sWla + 32768 + kx), accZ, 0, 0, 0);
        accR = __builtin_amdgcn_mfma_f32_16x16x32_bf16(x, *(const bf16x8*)(WrR + ks * 32), accR, 0, 0, 0);
        accZ = __builtin_amdgcn_mfma_f32_16x16x32_bf16(x, *(const bf16x8*)(WrZ + ks * 32), accZ, 0, 0, 0);
      }
    }
    #pragma unroll
    for (int r = 0; r < 4; ++r) {
      const int row = row0 + lk * 4 + r;  // C/D: row = (lane>>4)*4 + reg
      float pr = accR[r] + bR, pz = accZ[r] + bZ;
      if (layer == 0) {
        const float* xf = X0 + (size_t)(t * 64 + row) * 3072 + jl;
        pr += xf[0]; pz += xf[1024];
      }
      float rv = sigm(pr);
      z_reg[r] = sigm(pz);
      unsigned v = f2bf(rv * h_reg[r]);
      u16* p = RHl + (size_t)(t * 64 + row) * 1024 + jl;
      asm volatile("global_store_short %0, %1, off sc1" :: "v"(p), "v"(v));
    }
    arrive(myFlag, 2 * t + 1, tid);
    // ================= phase B: candidate + state update =================
    waitg64(fSelf, 2 * t + 1, tid);
    const u16* rp = RHl + (size_t)t * 65536 + (size_t)(row0 + la) * 1024 + lk * 8;
    f32x4 accH = {0.f, 0.f, 0.f, 0.f};
    if (layer == 0) {
      #pragma unroll 16
      for (int ks = 0; ks < 32; ++ks) {
        const int kx = (ks * 64 + lk * 16) ^ xorv;
        bf16x8 a = *(const bf16x8*)(rp + ks * 32);
        accH = __builtin_amdgcn_mfma_f32_16x16x32_bf16(a, *(const bf16x8*)(sWla + 65536 + kx), accH, 0, 0, 0);
      }
    } else {
      const u16* xp = H0seq + (size_t)t * 65536 + (size_t)(row0 + la) * 1024 + lk * 8;
      #pragma unroll 8
      for (int ks = 0; ks < 32; ++ks) {
        const int kx = (ks * 64 + lk * 16) ^ xorv;
        bf16x8 a = *(const bf16x8*)(rp + ks * 32);
        bf16x8 x = *(const bf16x8*)(xp + ks * 32);
        accH = __builtin_amdgcn_mfma_f32_16x16x32_bf16(a, *(const bf16x8*)(sWla + 65536 + kx), accH, 0, 0, 0);
        accH = __builtin_amdgcn_mfma_f32_16x16x32_bf16(x, *(const bf16x8*)(WrH + ks * 32), accH, 0, 0, 0);
      }
    }
    #pragma unroll
    for (int r = 0; r < 4; ++r) {
      const int row = row0 + lk * 4 + r;
      float pre = accH[r] + bH;
      if (layer == 0) pre += X0[(size_t)(t * 64 + row) * 3072 + 2048 + jl];
      float hc = tanh_f(pre);
      float hn = h_reg[r] + z_reg[r] * (hc - h_reg[r]);  // (1-z)h + z*hcand
      h_reg[r] = hn;
      unsigned v = f2bf(hn);
      u16* p = Hseq + (size_t)(t * 64 + row) * 1024 + jl;
      asm volatile("global_store_short %0, %1, off sc1" :: "v"(p), "v"(v));
      if (t == 63) houtf[layer * 65536 + row * 1024 + jl] = hn;
    }
    arrive(myFlag, 2 * t + 2, tid);
  }
}

// ---------------- host launch ----------------
extern "C" void kernel_launch(void* const* d_in, const int* in_sizes, int n_in,
                              void* d_out, int out_size, void* d_ws, size_t ws_size,
                              hipStream_t stream) {
  const int* inputs = (const int*)d_in[0];
  const float* hidden = (const float*)d_in[1];
  const float* emb = (const float*)d_in[2];
  const float* Wx = (const float*)d_in[3];
  const float* Ur = (const float*)d_in[4];
  const float* br = (const float*)d_in[5];
  const float* Wz = (const float*)d_in[6];
  const float* Uz = (const float*)d_in[7];
  const float* bz = (const float*)d_in[8];
  const float* Wh = (const float*)d_in[9];
  const float* Uh = (const float*)d_in[10];
  const float* bh = (const float*)d_in[11];
  const float* decW = (const float*)d_in[12];
  const float* decb = (const float*)d_in[13];
  float* out = (float*)d_out;

  char* ws = (char*)d_ws;
  size_t off = 0;
  auto alloc = [&](size_t bytes) { char* p = ws + off; off += (bytes + 255) & ~(size_t)255; return p; };
  unsigned* flags = (unsigned*)alloc(4096);   // [0..63]=L0, [64..127]=L1
  u16* hinitb = (u16*)alloc((size_t)2 * 64 * 1024 * 2);
  u16* xe     = (u16*)alloc((size_t)4096 * 1024 * 2);
  u16* Wcat0b = (u16*)alloc((size_t)3072 * 1024 * 2);
  u16* Wcat1b = (u16*)alloc((size_t)3072 * 1024 * 2);
  u16* Ucat0b = (u16*)alloc((size_t)3072 * 1024 * 2);
  u16* Ucat1b = (u16*)alloc((size_t)3072 * 1024 * 2);
  u16* decWb  = (u16*)alloc((size_t)32000 * 1024 * 2);
  float* X0   = (float*)alloc((size_t)4096 * 3072 * 4);
  u16* H0seq  = (u16*)alloc((size_t)4096 * 1024 * 2);
  u16* H1seq  = (u16*)alloc((size_t)4096 * 1024 * 2);
  u16* RH0    = (u16*)alloc((size_t)4096 * 1024 * 2);
  u16* RH1    = (u16*)alloc((size_t)4096 * 1024 * 2);

  hipMemsetAsync(flags, 0, 4096, stream);
  k_cvtv<<<128, 256, 0, stream>>>(hidden, hinitb, 32768);
  k_pack3<<<3072, 256, 0, stream>>>(Wx, Wz, Wh, 0, Wcat0b);
  k_pack3<<<3072, 256, 0, stream>>>(Wx, Wz, Wh, 1048576, Wcat1b);
  k_pack3<<<3072, 256, 0, stream>>>(Ur, Uz, Uh, 0, Ucat0b);
  k_pack3<<<3072, 256, 0, stream>>>(Ur, Uz, Uh, 1048576, Ucat1b);
  k_embed<<<4096, 256, 0, stream>>>(inputs, emb, xe);
  k_cvtv<<<4096, 256, 0, stream>>>(decW, decWb, 8192000);

  // layer-0 x-projections for all timesteps: [4096,1024] @ [3072,1024]^T
  gemm_bt<<<768, 256, 0, stream>>>(xe, Wcat0b, X0, 4096, 3072, 1024, 32);

  // fused: weight-stationary recurrence (blocks 0..127) + flag-chasing decoder (128..252)
  (void)hipFuncSetAttribute(reinterpret_cast<const void*>(&k_fused),
                            hipFuncAttributeMaxDynamicSharedMemorySize, 98304);
  k_fused<<<253, 256, 98304, stream>>>(hinitb, hidden, X0, Ucat0b, Ucat1b, Wcat1b,
                                       br, bz, bh, H0seq, H1seq, RH0, RH1,
                                       decWb, decb, out, flags);
}